// Round 1
// baseline (632.880 us; speedup 1.0000x reference)
//
#include <hip/hip_runtime.h>
#include <math.h>

#define N_NODES 50000
#define DIM 64
#define NE 800000

// ---------------------------------------------------------------------------
// ws layout (floats):
//   Q    : [N*DIM)            offset 0
//   K    : [N*DIM)            offset N*DIM
//   V    : [N*DIM)            offset 2*N*DIM
//   attn : [NE)               offset 3*N*DIM
//   g_max (uint), g_sum (float) after that
// ---------------------------------------------------------------------------

__global__ __launch_bounds__(256) void k_qkv(
    const float* __restrict__ x,
    const float* __restrict__ Wq, const float* __restrict__ bq,
    const float* __restrict__ Wk, const float* __restrict__ bk,
    const float* __restrict__ Wv, const float* __restrict__ bv,
    float* __restrict__ Q, float* __restrict__ K, float* __restrict__ V)
{
    __shared__ float WqT[DIM * DIM];
    __shared__ float WkT[DIM * DIM];
    __shared__ float WvT[DIM * DIM];
    __shared__ float xs[4][DIM];

    const int tid = threadIdx.x;
    // Stage weights transposed: WT[j][d] = W[d][j]  (bank-conflict-free reads)
    for (int t = tid; t < DIM * DIM; t += 256) {
        int d = t >> 6, j = t & 63;
        WqT[j * DIM + d] = Wq[t];
        WkT[j * DIM + d] = Wk[t];
        WvT[j * DIM + d] = Wv[t];
    }
    __syncthreads();

    const int ln = tid >> 6;   // local node 0..3 (one wave per node)
    const int d  = tid & 63;   // output dim
    const float bqv = bq[d], bkv = bk[d], bvv = bv[d];

    for (int base = blockIdx.x * 4; base < N_NODES; base += gridDim.x * 4) {
        __syncthreads();
        if (base + (tid >> 6) < N_NODES)
            xs[tid >> 6][tid & 63] = x[(size_t)base * DIM + tid];
        __syncthreads();
        int node = base + ln;
        if (node < N_NODES) {
            float aq = bqv, ak = bkv, av = bvv;
            #pragma unroll
            for (int j = 0; j < DIM; ++j) {
                float xv = xs[ln][j];                 // LDS broadcast
                aq += xv * WqT[j * DIM + d];          // 2-way bank alias: free
                ak += xv * WkT[j * DIM + d];
                av += xv * WvT[j * DIM + d];
            }
            Q[(size_t)node * DIM + d] = aq;
            K[(size_t)node * DIM + d] = ak;
            V[(size_t)node * DIM + d] = av;
        }
    }
}

// out[0:N*DIM) = x, out[N*DIM:2*N*DIM) = coord; reset softmax scalars
__global__ __launch_bounds__(256) void k_init(
    const float* __restrict__ x, const float* __restrict__ coord,
    float* __restrict__ out, unsigned int* __restrict__ g_max,
    float* __restrict__ g_sum)
{
    int i = blockIdx.x * 256 + threadIdx.x;
    const int total = N_NODES * DIM;
    if (i < total)            out[i] = x[i];
    else if (i < 2 * total)   out[i] = coord[i - total];
    if (i == 0) { *g_max = 0u; *g_sum = 0.0f; }
}

// attn[e] = dot(Q[row], K[col]); global max via monotone-key atomicMax
__global__ __launch_bounds__(256) void k_attn(
    const int* __restrict__ eidx,
    const float* __restrict__ Q, const float* __restrict__ K,
    float* __restrict__ attn, unsigned int* __restrict__ g_max)
{
    __shared__ float red[4];
    int e = blockIdx.x * 256 + threadIdx.x;
    float val = -1e30f;
    if (e < NE) {
        int r = eidx[e], c = eidx[NE + e];
        const float4* qr = (const float4*)(Q + (size_t)r * DIM);
        const float4* kr = (const float4*)(K + (size_t)c * DIM);
        float acc = 0.0f;
        #pragma unroll
        for (int j = 0; j < DIM / 4; ++j) {
            float4 a = qr[j], b = kr[j];
            acc += a.x * b.x + a.y * b.y + a.z * b.z + a.w * b.w;
        }
        attn[e] = acc;
        val = acc;
    }
    #pragma unroll
    for (int off = 32; off; off >>= 1)
        val = fmaxf(val, __shfl_xor(val, off));
    if ((threadIdx.x & 63) == 0) red[threadIdx.x >> 6] = val;
    __syncthreads();
    if (threadIdx.x == 0) {
        float m = fmaxf(fmaxf(red[0], red[1]), fmaxf(red[2], red[3]));
        unsigned int b = __float_as_uint(m);
        unsigned int key = (b & 0x80000000u) ? ~b : (b | 0x80000000u);
        atomicMax(g_max, key);
    }
}

// attn[e] = exp(attn[e]-max); g_sum += block partial
__global__ __launch_bounds__(256) void k_expsum(
    float* __restrict__ attn, const unsigned int* __restrict__ g_max,
    float* __restrict__ g_sum)
{
    __shared__ float red[4];
    unsigned int key = *g_max;
    unsigned int b = (key & 0x80000000u) ? (key & 0x7fffffffu) : ~key;
    float m = __uint_as_float(b);
    int e = blockIdx.x * 256 + threadIdx.x;
    float p = 0.0f;
    if (e < NE) {
        p = __expf(attn[e] - m);
        attn[e] = p;
    }
    #pragma unroll
    for (int off = 32; off; off >>= 1) p += __shfl_xor(p, off);
    if ((threadIdx.x & 63) == 0) red[threadIdx.x >> 6] = p;
    __syncthreads();
    if (threadIdx.x == 0)
        atomicAdd(g_sum, red[0] + red[1] + red[2] + red[3]);
}

// one wave per edge; lane = dim. Scatter-add into out via f32 atomics.
__global__ __launch_bounds__(256) void k_scatter(
    const int* __restrict__ eidx, const float* __restrict__ V,
    const float* __restrict__ coord, const float* __restrict__ attn,
    const float* __restrict__ Wc, const float* __restrict__ bc,
    const float* __restrict__ g_sum,
    float* __restrict__ out_x, float* __restrict__ out_c)
{
    const int lane = threadIdx.x & 63;
    const int e = (blockIdx.x * 256 + threadIdx.x) >> 6;
    if (e >= NE) return;
    const float inv = 1.0f / *g_sum;
    const int r = eidx[e], c = eidx[NE + e];
    const float w = attn[e] * inv;

    float cr = coord[(size_t)r * DIM + lane];
    float cc = coord[(size_t)c * DIM + lane];
    float dxv = cr - cc;
    float d2 = dxv * dxv;
    #pragma unroll
    for (int off = 32; off; off >>= 1) d2 += __shfl_xor(d2, off);
    float dist = sqrtf(d2);

    float vv = V[(size_t)c * DIM + lane];
    atomicAdd(out_x + (size_t)r * DIM + lane, w * vv);
    float dc = w * (dist * Wc[lane] + bc[lane]) * dxv;
    atomicAdd(out_c + (size_t)r * DIM + lane, dc);
}

extern "C" void kernel_launch(void* const* d_in, const int* in_sizes, int n_in,
                              void* d_out, int out_size, void* d_ws, size_t ws_size,
                              hipStream_t stream)
{
    const float* x     = (const float*)d_in[0];
    const float* coord = (const float*)d_in[1];
    const float* Wq    = (const float*)d_in[2];
    const float* bq    = (const float*)d_in[3];
    const float* Wk    = (const float*)d_in[4];
    const float* bk    = (const float*)d_in[5];
    const float* Wv    = (const float*)d_in[6];
    const float* bv    = (const float*)d_in[7];
    const float* Wc    = (const float*)d_in[8];
    const float* bc    = (const float*)d_in[9];
    const int*   eidx  = (const int*)d_in[10];

    float* out   = (float*)d_out;
    float* ws    = (float*)d_ws;
    float* Q     = ws;
    float* K     = ws + (size_t)N_NODES * DIM;
    float* V     = ws + (size_t)2 * N_NODES * DIM;
    float* attn  = ws + (size_t)3 * N_NODES * DIM;
    unsigned int* g_max = (unsigned int*)(attn + NE);
    float* g_sum = (float*)(g_max + 1);

    float* out_x = out;
    float* out_c = out + (size_t)N_NODES * DIM;

    // 1. per-node QKV projections
    k_qkv<<<2048, 256, 0, stream>>>(x, Wq, bq, Wk, bk, Wv, bv, Q, K, V);

    // 2. residual init + scalar reset
    k_init<<<(2 * N_NODES * DIM + 255) / 256, 256, 0, stream>>>(
        x, coord, out, g_max, g_sum);

    // 3. logits + global max
    k_attn<<<(NE + 255) / 256, 256, 0, stream>>>(eidx, Q, K, attn, g_max);

    // 4. exp + global sum
    k_expsum<<<(NE + 255) / 256, 256, 0, stream>>>(attn, g_max, g_sum);

    // 5. weighted scatter (one wave per edge)
    k_scatter<<<(NE + 3) / 4, 256, 0, stream>>>(
        eidx, V, coord, attn, Wc, bc, g_sum, out_x, out_c);
}